// Round 5
// baseline (75.930 us; speedup 1.0000x reference)
//
#include <hip/hip_runtime.h>
#include <cstdint>
#include <cstddef>

// Reference semantics: per-element fp32-rounded multiply, then a strictly
// sequential left-to-right fp32 add chain. FMA contraction changes low
// mantissa bits and flips output pulse bits -> keep contract OFF globally.
#pragma clang fp contract(off)

#define BATCH 256
#define IN_F  1024
#define OUT_F 1024

// ---------------------------------------------------------------------------
// decode: 32 pulse floats (0.0/1.0, MSB first) -> fp32 bit pattern
// ---------------------------------------------------------------------------
__device__ __forceinline__ uint32_t decode_bits(const float4* __restrict__ p) {
    uint32_t u = 0;
#pragma unroll
    for (int k = 0; k < 8; ++k) {
        float4 f = p[k];
        u = (u << 1) | ((__float_as_uint(f.x) >> 23) & 1u);
        u = (u << 1) | ((__float_as_uint(f.y) >> 23) & 1u);
        u = (u << 1) | ((__float_as_uint(f.z) >> 23) & 1u);
        u = (u << 1) | ((__float_as_uint(f.w) >> 23) & 1u);
    }
    return u;
}

// x pulses [B, IN, 32] -> x_f [B][IN] fp32 row-major
__global__ __launch_bounds__(256) void decode_x_kernel(const float* __restrict__ pulses,
                                                       float* __restrict__ xf) {
    int v = blockIdx.x * 256 + threadIdx.x;
    const float4* p = (const float4*)(pulses + (size_t)v * 32);
    xf[v] = __uint_as_float(decode_bits(p));
}

// w pulses [OUT, IN, 32] -> wt3 layout [IN/32][OUT][8 q][4 d] fp32 (dwords).
// i = sc*32 + q*4 + d. Pre-swizzle-friendly source layout for the gemm's
// global_load_lds staging (rule #21: linear LDS dest + swizzled global src).
__global__ __launch_bounds__(256) void decode_w_kernel(const float* __restrict__ pulses,
                                                       float* __restrict__ wt3) {
    int v = blockIdx.x * 256 + threadIdx.x;        // v = o*IN + i, reads coalesced
    int o = v >> 10;
    int i = v & (IN_F - 1);
    const float4* p = (const float4*)(pulses + (size_t)v * 32);
    float val = __uint_as_float(decode_bits(p));
    size_t idx = (((((size_t)(i >> 5)) << 10) + o) * 8 + ((i >> 2) & 7)) * 4 + (i & 3);
    wt3[idx] = val;
}

// ---------------------------------------------------------------------------
// GEMM: block = 512 threads = 8 waves; covers 64 o (lanes) x 16 b rows
// (wave wv handles rows wv and wv+8, R=2). Grid = 256 blocks = 1 per CU.
// w staged in LDS per 128-i chunk (double-buffered) via global_load_lds;
// per 32-i sub-chunk LDS layout [o=64][slot=8] float4, slot = q^(o&7).
// x is WAVE-UNIFORM: readfirstlane'd row base -> uniform float4 loads ->
// s_load through the scalar cache, consumed as SGPR operands of v_mul_f32.
// No x LDS traffic at all (R4's bottleneck: 2/3 of LDS-pipe issue was x).
// Strict left-to-right fp32 accumulation over i; mul then add, no FMA.
// ---------------------------------------------------------------------------
__global__ __launch_bounds__(512, 1) void gemm_encode_kernel(const float* __restrict__ xf,
                                                             const float* __restrict__ wt3,
                                                             float* __restrict__ out) {
#pragma clang fp contract(off)
    const int tid  = threadIdx.x;
    const int lane = tid & 63;
    const int wv   = tid >> 6;
    const int ot   = blockIdx.x & 15;              // o-tile
    const int bt   = blockIdx.x >> 4;              // b-tile
    const int o_g  = ot * 64 + lane;
    const int b0   = bt * 16;
    const int om   = lane & 7;

    __shared__ float4 wl[2][4][64][8];             // 64 KB: [buf][sc][o][slot]

    // wave-uniform x row bases (readfirstlane -> uniformity -> s_load)
    const int rb0 = __builtin_amdgcn_readfirstlane(b0 + wv);
    const int rb1 = __builtin_amdgcn_readfirstlane(b0 + wv + 8);
    const float* __restrict__ xrow0 = xf + ((size_t)rb0 << 10);
    const float* __restrict__ xrow1 = xf + ((size_t)rb1 << 10);

    // staging lane mapping (linear LDS dest): thread t -> (o = t>>3, s = t&7)
    const int o_st = wv * 8 + (lane >> 3);
    const int q_st = (lane & 7) ^ (lane >> 3);     // content q for physical slot s

    auto stage = [&](int bb, int c) {
#pragma unroll
        for (int sc = 0; sc < 4; ++sc) {
            int sc_g = c * 4 + sc;
            size_t dw = (((((size_t)sc_g) << 10) + (ot * 64 + o_st)) * 8 + q_st) * 4;
            const char* g = (const char*)(wt3 + dw);
            char* d = (char*)(&wl[bb][sc][0][0]) + wv * 1024;
            __builtin_amdgcn_global_load_lds(
                (const __attribute__((address_space(1))) void*)g,
                (__attribute__((address_space(3))) void*)d, 16, 0, 0);
        }
    };

    float acc0 = 0.0f, acc1 = 0.0f;

    auto compute = [&](int bb, int c, bool first) {
        const float4* xc0 = (const float4*)(xrow0 + (c << 7));  // uniform
        const float4* xc1 = (const float4*)(xrow1 + (c << 7));
#pragma unroll
        for (int sc = 0; sc < 4; ++sc) {
            float4 w4[8];
#pragma unroll
            for (int q = 0; q < 8; ++q) w4[q] = wl[bb][sc][lane][q ^ om];
#pragma unroll
            for (int q = 0; q < 8; ++q) {
                float4 xa = xc0[sc * 8 + q];       // s_load_dwordx4 (uniform)
                float4 xb_ = xc1[sc * 8 + q];
                float4 wq = w4[q];
                if (first && sc == 0 && q == 0) {
                    acc0 = xa.x * wq.x;            // scan init: acc = prods[0]
                    acc1 = xb_.x * wq.x;
                } else {
                    acc0 = acc0 + (xa.x * wq.x);
                    acc1 = acc1 + (xb_.x * wq.x);
                }
                acc0 = acc0 + (xa.y * wq.y);
                acc1 = acc1 + (xb_.y * wq.y);
                acc0 = acc0 + (xa.z * wq.z);
                acc1 = acc1 + (xb_.z * wq.z);
                acc0 = acc0 + (xa.w * wq.w);
                acc1 = acc1 + (xb_.w * wq.w);
            }
        }
    };

    // prologue
    stage(0, 0);
    __syncthreads();                                // drains vmcnt before use

    int cur = 0;
#pragma unroll 1
    for (int c = 0; c < 8; ++c) {
        if (c < 7) stage(cur ^ 1, c + 1);           // issue next-chunk loads early
        compute(cur, c, c == 0);
        __syncthreads();                            // vmcnt+lgkm drain + barrier
        cur ^= 1;
    }

    // ---- encode both accumulators back to 32 pulse floats ----
    const float accs[2] = {acc0, acc1};
#pragma unroll
    for (int r = 0; r < 2; ++r) {
        uint32_t u = __float_as_uint(accs[r]);
        int b = b0 + wv + r * 8;
        float4* dstp = (float4*)(out + (((size_t)b << 10) + o_g) * 32);
#pragma unroll
        for (int k = 0; k < 8; ++k) {
            float4 f;
            f.x = (float)((u >> (31 - 4 * k)) & 1u);
            f.y = (float)((u >> (30 - 4 * k)) & 1u);
            f.z = (float)((u >> (29 - 4 * k)) & 1u);
            f.w = (float)((u >> (28 - 4 * k)) & 1u);
            dstp[k] = f;
        }
    }
}

extern "C" void kernel_launch(void* const* d_in, const int* in_sizes, int n_in,
                              void* d_out, int out_size, void* d_ws, size_t ws_size,
                              hipStream_t stream) {
    const float* x_pulses = (const float*)d_in[0];   // [B, IN, 32]
    const float* w_pulses = (const float*)d_in[1];   // [OUT, IN, 32]
    float* out = (float*)d_out;                      // [B, OUT, 32]

    float* xf  = (float*)d_ws;                       // 1 MB
    float* wt3 = xf + (size_t)BATCH * IN_F;          // 4 MB

    decode_x_kernel<<<(BATCH * IN_F) / 256, 256, 0, stream>>>(x_pulses, xf);
    decode_w_kernel<<<(OUT_F * IN_F) / 256, 256, 0, stream>>>(w_pulses, wt3);
    gemm_encode_kernel<<<256, 512, 0, stream>>>(xf, wt3, out);
}

// Round 6
// 70.471 us; speedup vs baseline: 1.0775x; 1.0775x over previous
//
#include <hip/hip_runtime.h>
#include <cstdint>
#include <cstddef>

// Reference semantics: per-element fp32-rounded multiply, then a strictly
// sequential left-to-right fp32 add chain. FMA contraction changes low
// mantissa bits and flips output pulse bits -> keep contract OFF globally.
#pragma clang fp contract(off)

#define BATCH 256
#define IN_F  1024
#define OUT_F 1024

// ---------------------------------------------------------------------------
// decode: 32 pulse floats (0.0/1.0, MSB first) -> fp32 bit pattern
// ---------------------------------------------------------------------------
__device__ __forceinline__ uint32_t decode_bits(const float4* __restrict__ p) {
    uint32_t u = 0;
#pragma unroll
    for (int k = 0; k < 8; ++k) {
        float4 f = p[k];
        u = (u << 1) | ((__float_as_uint(f.x) >> 23) & 1u);
        u = (u << 1) | ((__float_as_uint(f.y) >> 23) & 1u);
        u = (u << 1) | ((__float_as_uint(f.z) >> 23) & 1u);
        u = (u << 1) | ((__float_as_uint(f.w) >> 23) & 1u);
    }
    return u;
}

// Fused decode: blocks [0,1024) decode x -> xf[B][IN]; blocks [1024,5120)
// decode w -> wt3 [IN/32][OUT][8 q][4 d] (pre-swizzled source layout for the
// gemm's global_load_lds staging; rule #21: linear LDS dest + swizzled src).
__global__ __launch_bounds__(256) void decode_kernel(const float* __restrict__ xp,
                                                     const float* __restrict__ wp,
                                                     float* __restrict__ xf,
                                                     float* __restrict__ wt3) {
    const int bid = blockIdx.x;
    const int tid = threadIdx.x;
    if (bid < (BATCH * IN_F) / 256) {
        int v = bid * 256 + tid;
        const float4* p = (const float4*)(xp + (size_t)v * 32);
        xf[v] = __uint_as_float(decode_bits(p));
    } else {
        int v = (bid - (BATCH * IN_F) / 256) * 256 + tid;   // v = o*IN + i
        int o = v >> 10;
        int i = v & (IN_F - 1);
        const float4* p = (const float4*)(wp + (size_t)v * 32);
        float val = __uint_as_float(decode_bits(p));
        size_t idx = (((((size_t)(i >> 5)) << 10) + o) * 8 + ((i >> 2) & 7)) * 4 + (i & 3);
        wt3[idx] = val;
    }
}

// ---------------------------------------------------------------------------
// GEMM: block = 512 threads = 8 waves; 64 o (lanes) x 16 b rows (wave wv
// handles rows wv and wv+8). Grid = 256 blocks = 1 per CU.
// w staged in LDS per 128-i chunk (double-buffered, global_load_lds), bank-
// conflict-free layout [o=64][slot=8] float4 with slot = q^(o&7)  [as R4].
// x delivered via v_readlane: per chunk each wave loads its two rows as 4
// coalesced per-lane dwords (lane = i), then broadcasts each element with a
// literal-lane readlane. Removes ALL x LDS traffic (R4's bottleneck: x
// broadcasts were 2/3 of the CU-shared LDS pipe) at +1 VALU op per MAC pair.
// Strict left-to-right fp32 accumulation over i; mul then add, no FMA.
// ---------------------------------------------------------------------------
__global__ __launch_bounds__(512, 1) void gemm_encode_kernel(const float* __restrict__ xf,
                                                             const float* __restrict__ wt3,
                                                             float* __restrict__ out) {
#pragma clang fp contract(off)
    const int tid  = threadIdx.x;
    const int lane = tid & 63;
    const int wv   = tid >> 6;
    const int ot   = blockIdx.x & 15;              // o-tile
    const int bt   = blockIdx.x >> 4;              // b-tile
    const int o_g  = ot * 64 + lane;
    const int b0   = bt * 16;
    const int om   = lane & 7;

    __shared__ float4 wl[2][4][64][8];             // 64 KB: [buf][sc][o][slot]

    const float* __restrict__ xr0 = xf + ((size_t)(b0 + wv) << 10);
    const float* __restrict__ xr1 = xf + ((size_t)(b0 + wv + 8) << 10);

    // staging lane mapping (linear LDS dest): thread t -> (o = t>>3, s = t&7)
    const int o_st = wv * 8 + (lane >> 3);
    const int q_st = (lane & 7) ^ (lane >> 3);     // content q for physical slot s

    auto stage = [&](int bb, int c) {
#pragma unroll
        for (int sc = 0; sc < 4; ++sc) {
            int sc_g = c * 4 + sc;
            size_t dw = (((((size_t)sc_g) << 10) + (ot * 64 + o_st)) * 8 + q_st) * 4;
            const char* g = (const char*)(wt3 + dw);
            char* d = (char*)(&wl[bb][sc][0][0]) + wv * 1024;
            __builtin_amdgcn_global_load_lds(
                (const __attribute__((address_space(1))) void*)g,
                (__attribute__((address_space(3))) void*)d, 16, 0, 0);
        }
    };

    float acc0 = 0.0f, acc1 = 0.0f;

    // xa* hold i = chunk*128 + [0,64) at lane = i; xb* hold i = +[64,128).
    auto compute = [&](int bb, float xa0, float xb0, float xa1, float xb1, bool first) {
#pragma unroll
        for (int sc = 0; sc < 4; ++sc) {
            float4 w4[8];
#pragma unroll
            for (int q = 0; q < 8; ++q) w4[q] = wl[bb][sc][lane][q ^ om];
            const bool loh = (sc < 2);             // which x register pair
            const int base = (sc & 1) * 32;        // lane base within it
#pragma unroll
            for (int q = 0; q < 8; ++q) {
                float wq[4] = {w4[q].x, w4[q].y, w4[q].z, w4[q].w};
#pragma unroll
                for (int d = 0; d < 4; ++d) {
                    const int ll = base + q * 4 + d;   // literal lane index
                    float x0 = __uint_as_float(__builtin_amdgcn_readlane(
                        __float_as_uint(loh ? xa0 : xb0), ll));
                    float x1 = __uint_as_float(__builtin_amdgcn_readlane(
                        __float_as_uint(loh ? xa1 : xb1), ll));
                    if (first && sc == 0 && q == 0 && d == 0) {
                        acc0 = x0 * wq[0];             // scan init: acc = prods[0]
                        acc1 = x1 * wq[0];
                    } else {
                        acc0 = acc0 + (x0 * wq[d]);
                        acc1 = acc1 + (x1 * wq[d]);
                    }
                }
            }
        }
    };

    // prologue: stage chunk 0 (w) and load chunk 0's x registers
    stage(0, 0);
    float xa0 = xr0[lane], xb0 = xr0[64 + lane];
    float xa1 = xr1[lane], xb1 = xr1[64 + lane];
    __syncthreads();                                // drains vmcnt before use

    int cur = 0;
#pragma unroll 1
    for (int c = 0; c < 8; ++c) {
        float na0 = 0.f, nb0 = 0.f, na1 = 0.f, nb1 = 0.f;
        if (c < 7) {
            stage(cur ^ 1, c + 1);                  // issue next w-chunk loads
            const int off = (c + 1) << 7;           // and next x-chunk loads
            na0 = xr0[off + lane]; nb0 = xr0[off + 64 + lane];
            na1 = xr1[off + lane]; nb1 = xr1[off + 64 + lane];
        }
        compute(cur, xa0, xb0, xa1, xb1, c == 0);
        __syncthreads();                            // vmcnt+lgkm drain + barrier
        xa0 = na0; xb0 = nb0; xa1 = na1; xb1 = nb1;
        cur ^= 1;
    }

    // ---- encode both accumulators back to 32 pulse floats ----
    const float accs[2] = {acc0, acc1};
#pragma unroll
    for (int r = 0; r < 2; ++r) {
        uint32_t u = __float_as_uint(accs[r]);
        int b = b0 + wv + r * 8;
        float4* dstp = (float4*)(out + (((size_t)b << 10) + o_g) * 32);
#pragma unroll
        for (int k = 0; k < 8; ++k) {
            float4 f;
            f.x = (float)((u >> (31 - 4 * k)) & 1u);
            f.y = (float)((u >> (30 - 4 * k)) & 1u);
            f.z = (float)((u >> (29 - 4 * k)) & 1u);
            f.w = (float)((u >> (28 - 4 * k)) & 1u);
            dstp[k] = f;
        }
    }
}

extern "C" void kernel_launch(void* const* d_in, const int* in_sizes, int n_in,
                              void* d_out, int out_size, void* d_ws, size_t ws_size,
                              hipStream_t stream) {
    const float* x_pulses = (const float*)d_in[0];   // [B, IN, 32]
    const float* w_pulses = (const float*)d_in[1];   // [OUT, IN, 32]
    float* out = (float*)d_out;                      // [B, OUT, 32]

    float* xf  = (float*)d_ws;                       // 1 MB
    float* wt3 = xf + (size_t)BATCH * IN_F;          // 4 MB

    decode_kernel<<<(BATCH * IN_F + OUT_F * IN_F) / 256, 256, 0, stream>>>(
        x_pulses, w_pulses, xf, wt3);
    gemm_encode_kernel<<<256, 512, 0, stream>>>(xf, wt3, out);
}